// Round 10
// baseline (635.675 us; speedup 1.0000x reference)
//
#include <hip/hip_runtime.h>
#include <cstdint>

#define S 2048
#define E 1024
#define NH 16
#define HD 64
#define KTOP 32
#define BANDU 1e-3f       // unscaled-score ambiguity band
#define NPMAX 48

typedef __attribute__((ext_vector_type(8))) short short8v;   // bf16x8 frag
typedef __attribute__((ext_vector_type(4))) float f32x4;

// ---------------- fp32 GEMM: C[M,N] = X[M,K] @ W[N,K]^T + bias ----------------
__global__ __launch_bounds__(256)
void gemm_xwT(const float* __restrict__ X, const float* __restrict__ W,
              const float* __restrict__ bias, float* __restrict__ C,
              int M, int N, int K) {
  __shared__ float Xs[16][68];
  __shared__ float Ws[16][68];
  const int bm = blockIdx.x * 64;
  const int bn = blockIdx.y * 64;
  const int tid = threadIdx.x;
  const int tx = tid & 15, ty = tid >> 4;
  const int r = tid & 63, kk = (tid >> 6) * 4;
  float acc[4][4] = {};
  for (int k0 = 0; k0 < K; k0 += 16) {
    __syncthreads();
    {
      float4 xv = *(const float4*)(X + (size_t)(bm + r) * K + k0 + kk);
      Xs[kk + 0][r] = xv.x; Xs[kk + 1][r] = xv.y;
      Xs[kk + 2][r] = xv.z; Xs[kk + 3][r] = xv.w;
      float4 wv4 = *(const float4*)(W + (size_t)(bn + r) * K + k0 + kk);
      Ws[kk + 0][r] = wv4.x; Ws[kk + 1][r] = wv4.y;
      Ws[kk + 2][r] = wv4.z; Ws[kk + 3][r] = wv4.w;
    }
    __syncthreads();
#pragma unroll
    for (int k = 0; k < 16; ++k) {
      float4 a = *(const float4*)&Xs[k][tx * 4];
      float4 b = *(const float4*)&Ws[k][ty * 4];
      float av[4] = {a.x, a.y, a.z, a.w};
      float bv[4] = {b.x, b.y, b.z, b.w};
#pragma unroll
      for (int i = 0; i < 4; ++i)
#pragma unroll
        for (int j = 0; j < 4; ++j)
          acc[i][j] = fmaf(av[i], bv[j], acc[i][j]);
    }
  }
  const float4 bv4 = *(const float4*)(bias + bn + ty * 4);
  const float bb[4] = {bv4.x, bv4.y, bv4.z, bv4.w};
#pragma unroll
  for (int i = 0; i < 4; ++i) {
    float4 o;
    o.x = acc[i][0] + bb[0];
    o.y = acc[i][1] + bb[1];
    o.z = acc[i][2] + bb[2];
    o.w = acc[i][3] + bb[3];
    *(float4*)(C + (size_t)(bm + tx * 4 + i) * N + bn + ty * 4) = o;
  }
}

// ------------------------------ helpers --------------------------------------
__device__ __forceinline__ unsigned fordu(float x) {
  unsigned u = __float_as_uint(x);
  return (u & 0x80000000u) ? ~u : (u | 0x80000000u);
}
__device__ __forceinline__ float invfordu(unsigned f) {
  unsigned u = (f & 0x80000000u) ? (f ^ 0x80000000u) : ~f;
  return __uint_as_float(u);
}
__device__ __forceinline__ unsigned long long fordu64(double x) {
  unsigned long long u = (unsigned long long)__double_as_longlong(x);
  return (u >> 63) ? ~u : (u | 0x8000000000000000ULL);
}
__device__ __forceinline__ unsigned long long shflx64(unsigned long long v, int off) {
  int lo = __shfl_xor((int)(unsigned)(v & 0xFFFFFFFFULL), off);
  int hi = __shfl_xor((int)(unsigned)(v >> 32), off);
  return ((unsigned long long)(unsigned)hi << 32) | (unsigned)lo;
}
__device__ __forceinline__ double shflx_f64(double v, int off) {
  unsigned long long u = (unsigned long long)__double_as_longlong(v);
  return __longlong_as_double((long long)shflx64(u, off));
}
// round-to-nearest-even bf16 split: x ~= hi + lo (both bf16)
__device__ __forceinline__ void splitbf(float x, unsigned short& hs, unsigned short& ls) {
  unsigned u = __float_as_uint(x);
  unsigned r = (u + 0x7FFFu + ((u >> 16) & 1u)) & 0xFFFF0000u;
  hs = (unsigned short)(r >> 16);
  const float lo = x - __uint_as_float(r);
  unsigned ul = __float_as_uint(lo);
  ls = (unsigned short)((ul + 0x7FFFu + ((ul >> 16) & 1u)) >> 16);
}
// fp64 projection element: sum_e x[e]*w[e] (rare band path; biases are zero)
__device__ double proj64(const float* __restrict__ xrow, const float* __restrict__ wrow) {
  double a0 = 0.0, a1 = 0.0;
  for (int e = 0; e < E; e += 8) {
    const float4 x0 = *(const float4*)(xrow + e);
    const float4 w0 = *(const float4*)(wrow + e);
    const float4 x1 = *(const float4*)(xrow + e + 4);
    const float4 w1 = *(const float4*)(wrow + e + 4);
    a0 = fma((double)x0.x, (double)w0.x, a0);
    a0 = fma((double)x0.y, (double)w0.y, a0);
    a0 = fma((double)x0.z, (double)w0.z, a0);
    a0 = fma((double)x0.w, (double)w0.w, a0);
    a1 = fma((double)x1.x, (double)w1.x, a1);
    a1 = fma((double)x1.y, (double)w1.y, a1);
    a1 = fma((double)x1.z, (double)w1.z, a1);
    a1 = fma((double)x1.w, (double)w1.w, a1);
  }
  return a0 + a1;
}

// ==== fused: bf16-split MFMA scores + exact top-k + band fp64 + epilogue ======
// block = 512 thr (8 waves) x 16 q-rows x 1 head; wave owns 2 rows.
// per-lane score layout for row: idx(i,c): x=i*256+2l, y=+1, z=+128, w=+129
__global__ __launch_bounds__(512, 2)
void attn_mfma(const float* __restrict__ QP, const float* __restrict__ KP,
               const float* __restrict__ VP,
               const float* __restrict__ QRAW, const float* __restrict__ KRAW,
               const float* __restrict__ WQ, const float* __restrict__ WK,
               float* __restrict__ CTX, float* __restrict__ AM) {
  __shared__ short khi[128 * 64];          // 16KB, 16B-slot XOR swizzle by key&7
  __shared__ short klo[128 * 64];          // 16KB
  __shared__ short qhi[16 * 64];           // 2KB, swizzle by row&7
  __shared__ short qlo[16 * 64];           // 2KB
  __shared__ float sbuf[16][132];          // 8.4KB chunk scores [row][key]
  __shared__ unsigned long long cand[8][64];  // 4KB

  const int h = blockIdx.y;
  const int r0 = blockIdx.x * 16;
  const int tid = threadIdx.x;
  const int lane = tid & 63, wid = tid >> 6;
  const int wrow0 = wid * 2, wrow1 = wid * 2 + 1;

  // ---- stage Q (16x64), bf16 split ----
  if (tid < 256) {
    const int row = tid >> 4, d0 = (tid & 15) * 4;
    const float4 qv = *(const float4*)(QP + (size_t)(r0 + row) * E + h * HD + d0);
    unsigned short h0, h1, h2, h3, l0, l1, l2, l3;
    splitbf(qv.x, h0, l0); splitbf(qv.y, h1, l1);
    splitbf(qv.z, h2, l2); splitbf(qv.w, h3, l3);
    const int off = row * 64 + ((((d0 >> 3) ^ (row & 7)) << 3) + (d0 & 4));
    uint2 uh = {(unsigned)h0 | ((unsigned)h1 << 16), (unsigned)h2 | ((unsigned)h3 << 16)};
    uint2 ul = {(unsigned)l0 | ((unsigned)l1 << 16), (unsigned)l2 | ((unsigned)l3 << 16)};
    *(uint2*)&qhi[off] = uh;
    *(uint2*)&qlo[off] = ul;
  }
  __syncthreads();

  // ---- A-frags (all 16 rows), once ----
  const int arow = lane & 15, akg = lane >> 4, asw = arow & 7;
  const short8v ah0 = *(const short8v*)&qhi[arow * 64 + ((akg ^ asw) << 3)];
  const short8v ah1 = *(const short8v*)&qhi[arow * 64 + (((4 + akg) ^ asw) << 3)];
  const short8v al0 = *(const short8v*)&qlo[arow * 64 + ((akg ^ asw) << 3)];
  const short8v al1 = *(const short8v*)&qlo[arow * 64 + (((4 + akg) ^ asw) << 3)];

  f32x4 g[2][8];   // all indices literal (macro-expanded) -> registers

  auto stageK = [&](int c) {
    const int key = tid >> 2, dq = tid & 3;
    const float* src = KP + (size_t)(c * 128 + key) * E + h * HD;
    const int krow = key * 64, ksw = key & 7;
#pragma unroll
    for (int q2 = 0; q2 < 4; ++q2) {
      const int d0 = dq * 16 + q2 * 4;
      const float4 kv = *(const float4*)(src + d0);
      unsigned short h0, h1, h2, h3, l0, l1, l2, l3;
      splitbf(kv.x, h0, l0); splitbf(kv.y, h1, l1);
      splitbf(kv.z, h2, l2); splitbf(kv.w, h3, l3);
      const int off = krow + ((((d0 >> 3) ^ ksw) << 3) + (d0 & 4));
      uint2 uh = {(unsigned)h0 | ((unsigned)h1 << 16), (unsigned)h2 | ((unsigned)h3 << 16)};
      uint2 ul = {(unsigned)l0 | ((unsigned)l1 << 16), (unsigned)l2 | ((unsigned)l3 << 16)};
      *(uint2*)&khi[off] = uh;
      *(uint2*)&klo[off] = ul;
    }
  };

  auto mfmaPhase = [&]() {
    const int bcol = (wid << 4) + (lane & 15);
    const int bkg = lane >> 4, bsw = bcol & 7;
    const short8v bh0 = *(const short8v*)&khi[bcol * 64 + ((bkg ^ bsw) << 3)];
    const short8v bh1 = *(const short8v*)&khi[bcol * 64 + (((4 + bkg) ^ bsw) << 3)];
    const short8v bl0 = *(const short8v*)&klo[bcol * 64 + ((bkg ^ bsw) << 3)];
    const short8v bl1 = *(const short8v*)&klo[bcol * 64 + (((4 + bkg) ^ bsw) << 3)];
    f32x4 acc = {0.f, 0.f, 0.f, 0.f};
    acc = __builtin_amdgcn_mfma_f32_16x16x32_bf16(ah0, bh0, acc, 0, 0, 0);
    acc = __builtin_amdgcn_mfma_f32_16x16x32_bf16(ah1, bh1, acc, 0, 0, 0);
    acc = __builtin_amdgcn_mfma_f32_16x16x32_bf16(ah0, bl0, acc, 0, 0, 0);
    acc = __builtin_amdgcn_mfma_f32_16x16x32_bf16(ah1, bl1, acc, 0, 0, 0);
    acc = __builtin_amdgcn_mfma_f32_16x16x32_bf16(al0, bh0, acc, 0, 0, 0);
    acc = __builtin_amdgcn_mfma_f32_16x16x32_bf16(al1, bh1, acc, 0, 0, 0);
    const int dr0 = (lane >> 4) << 2;
    sbuf[dr0 + 0][bcol] = acc[0];
    sbuf[dr0 + 1][bcol] = acc[1];
    sbuf[dr0 + 2][bcol] = acc[2];
    sbuf[dr0 + 3][bcol] = acc[3];
  };

#define GREAD(cc) { \
    const float2 ta = *(const float2*)&sbuf[wrow0][lane * 2]; \
    const float2 tb = *(const float2*)&sbuf[wrow1][lane * 2]; \
    if ((cc) & 1) { g[0][(cc) >> 1].z = ta.x; g[0][(cc) >> 1].w = ta.y; \
                    g[1][(cc) >> 1].z = tb.x; g[1][(cc) >> 1].w = tb.y; } \
    else          { g[0][(cc) >> 1].x = ta.x; g[0][(cc) >> 1].y = ta.y; \
                    g[1][(cc) >> 1].x = tb.x; g[1][(cc) >> 1].y = tb.y; } }

  stageK(0); __syncthreads(); mfmaPhase(); __syncthreads();
#define STEP(c) stageK(c); GREAD((c) - 1); __syncthreads(); mfmaPhase(); __syncthreads();
  STEP(1) STEP(2) STEP(3) STEP(4) STEP(5) STEP(6) STEP(7) STEP(8)
  STEP(9) STEP(10) STEP(11) STEP(12) STEP(13) STEP(14) STEP(15)
  GREAD(15);
#undef STEP
#undef GREAD

  // -------- selection + epilogue per owned row (round-5 logic, new idx) -------
#pragma unroll
  for (int rr = 0; rr < 2; ++rr) {
    const int row = r0 + (wid << 1) + rr;
    float gm[8];
#pragma unroll
    for (int i = 0; i < 8; ++i)
      gm[i] = fmaxf(fmaxf(g[rr][i].x, g[rr][i].y), fmaxf(g[rr][i].z, g[rr][i].w));
    float lm = fmaxf(fmaxf(fmaxf(gm[0], gm[1]), fmaxf(gm[2], gm[3])),
                     fmaxf(fmaxf(gm[4], gm[5]), fmaxf(gm[6], gm[7])));

    // threshold T = 34th-largest lane-max (guarantees top-34 coverage)
    float sk = lm;
#pragma unroll
    for (int k = 2; k <= 64; k <<= 1)
#pragma unroll
      for (int j = k >> 1; j; j >>= 1) {
        const float o = __shfl_xor(sk, j);
        const float mx = fmaxf(sk, o), mn = fminf(sk, o);
        const bool up = ((lane & k) == 0);
        sk = (((lane & j) == 0) == up) ? mx : mn;
      }
    const float T = __shfl(sk, 33);

    int cnt = 0;
#pragma unroll
    for (int i = 0; i < 8; ++i)
      cnt += (g[rr][i].x >= T) + (g[rr][i].y >= T) + (g[rr][i].z >= T) + (g[rr][i].w >= T);
    int pre = cnt;
#pragma unroll
    for (int off = 1; off < 64; off <<= 1) {
      const int y = __shfl_up(pre, off);
      if (lane >= off) pre += y;
    }
    const int n = __shfl(pre, 63);

    float mv = -INFINITY; int mi = 0;
    if (n <= 64) {
      cand[wid][lane] = 0ULL;
      __threadfence_block();
      int pos = pre - cnt;
#pragma unroll
      for (int i = 0; i < 8; ++i) {
        const int bx = i * 256 + lane * 2;
        if (g[rr][i].x >= T) cand[wid][pos++] = (((unsigned long long)fordu(g[rr][i].x)) << 32) | (unsigned)(2047 - bx);
        if (g[rr][i].y >= T) cand[wid][pos++] = (((unsigned long long)fordu(g[rr][i].y)) << 32) | (unsigned)(2047 - (bx + 1));
        if (g[rr][i].z >= T) cand[wid][pos++] = (((unsigned long long)fordu(g[rr][i].z)) << 32) | (unsigned)(2047 - (bx + 128));
        if (g[rr][i].w >= T) cand[wid][pos++] = (((unsigned long long)fordu(g[rr][i].w)) << 32) | (unsigned)(2047 - (bx + 129));
      }
      __threadfence_block();
      unsigned long long key = cand[wid][lane];
#pragma unroll
      for (int k = 2; k <= 64; k <<= 1)
#pragma unroll
        for (int j = k >> 1; j; j >>= 1) {
          const unsigned long long o = shflx64(key, j);
          const unsigned long long mx = key > o ? key : o;
          const unsigned long long mn = key > o ? o : key;
          const bool up = ((lane & k) == 0);
          key = (((lane & j) == 0) == up) ? mx : mn;
        }
      if (lane < n) {
        mv = invfordu((unsigned)(key >> 32));
        mi = 2047 - (int)(key & 0xFFFFFFFFu);
      }
    } else {
      // rare fallback (massive ties): exact pop-max loop
      float v32f = -INFINITY, v33f = -INFINITY;
      bool stop = false;
#pragma unroll 1
      for (int p = 0; p < NPMAX && !stop; ++p) {
        float M = lm;
#pragma unroll
        for (int off = 32; off; off >>= 1) M = fmaxf(M, __shfl_xor(M, off));
        int fp = 0x7FFFFFFF;
#pragma unroll
        for (int i = 7; i >= 0; --i) {
          const int base = i * 256 + lane * 2;
          if (g[rr][i].w == M) fp = base + 129;
          if (g[rr][i].z == M) fp = base + 128;
          if (g[rr][i].y == M) fp = base + 1;
          if (g[rr][i].x == M) fp = base;
        }
        const unsigned long long bal = __ballot(lm == M);
        int widx;
        if (__popcll(bal) == 1) {
          widx = __shfl(fp, __ffsll(bal) - 1);
        } else {
          int c2m = (lm == M) ? fp : 0x7FFFFFFF;
#pragma unroll
          for (int off = 32; off; off >>= 1) c2m = min(c2m, __shfl_xor(c2m, off));
          widx = c2m;
        }
        const int og = widx >> 8, rem = widx & 255;
        const int ol = (rem >> 1) & 63;
        const int oc = ((rem >> 7) << 1) | (rem & 1);
        const bool own = (lane == ol);
#pragma unroll
        for (int i = 0; i < 8; ++i)
          if (og == i && own) {
            if (oc == 0) g[rr][i].x = -INFINITY;
            else if (oc == 1) g[rr][i].y = -INFINITY;
            else if (oc == 2) g[rr][i].z = -INFINITY;
            else g[rr][i].w = -INFINITY;
            gm[i] = fmaxf(fmaxf(g[rr][i].x, g[rr][i].y), fmaxf(g[rr][i].z, g[rr][i].w));
          }
        float m8 = fmaxf(fmaxf(fmaxf(gm[0], gm[1]), fmaxf(gm[2], gm[3])),
                         fmaxf(fmaxf(gm[4], gm[5]), fmaxf(gm[6], gm[7])));
        lm = own ? m8 : lm;
        if (lane == p) { mv = M; mi = widx; }
        if (p == 33) {
          v32f = __shfl(mv, 31); v33f = __shfl(mv, 32);
          stop = (v32f - v33f > BANDU);
        } else if (p > 33) {
          stop = (M < v32f - BANDU);
        }
      }
      // convert packed widx positions to real indices
      if (mv != -INFINITY) {
        const int og = mi >> 8, rem = mi & 255;
        mi = og * 256 + ((rem >> 7) << 7) + (((rem >> 1) & 63) * 2) + (rem & 1);
      }
    }

    const float v32 = __shfl(mv, 31), v33 = __shfl(mv, 32);
    const bool bandHit = (v32 - v33 <= BANDU);
    bool IN = (lane < KTOP);
    if (bandHit) {   // ambiguous cut (rare, wave-uniform)
      const bool flg = (mv >= v32 - BANDU) && (mv <= v33 + BANDU);
      const unsigned long long fmask = __ballot(flg);
      const int nAbove = __popcll(__ballot((lane < KTOP) && !flg));
      const int need = KTOP - nAbove;
      const double qd = proj64(QRAW + (size_t)row * E, WQ + (size_t)(h * HD + lane) * E);
      double s64 = -INFINITY;
      unsigned long long t = fmask;
      while (t) {
        const int f = __ffsll(t) - 1; t &= t - 1;
        const int ki = __shfl(mi, f);
        const double kd = proj64(KRAW + (size_t)ki * E, WK + (size_t)(h * HD + lane) * E);
        double sacc = qd * kd;
#pragma unroll
        for (int off = 32; off; off >>= 1) sacc += shflx_f64(sacc, off);
        if (lane == f) s64 = sacc;
      }
      bool in2 = false;
      for (int t2 = 0; t2 < need; ++t2) {
        const unsigned long long sk2 = (flg && !in2) ? fordu64(s64) : 0ULL;
        unsigned long long mx = sk2;
#pragma unroll
        for (int off = 32; off; off >>= 1) {
          const unsigned long long o = shflx64(mx, off);
          if (o > mx) mx = o;
        }
        const unsigned long long wb = __ballot(flg && !in2 && sk2 == mx);
        if (lane == __ffsll(wb) - 1) in2 = true;
      }
      IN = ((lane < KTOP) && !flg) || in2;
    }

    // softmax over IN (unscaled scores; scale 1/8 inside exp)
    float x = IN ? mv : -INFINITY, m = x;
#pragma unroll
    for (int off = 32; off; off >>= 1) m = fmaxf(m, __shfl_xor(m, off));
    const float ee = IN ? expf((mv - m) * 0.125f) : 0.f;
    float z = ee;
#pragma unroll
    for (int off = 32; off; off >>= 1) z += __shfl_xor(z, off);
    const float w = ee / z;
    if (IN) atomicAdd(AM + (size_t)row * S + mi, w * 0.0625f);

    float accv = 0.f;
    if (!bandHit) {
      // common path: IN == lanes 0..31 -> static, independent gathers
#pragma unroll
      for (int i = 0; i < KTOP; ++i) {
        const float wi = __shfl(w, i);
        const int ii = __shfl(mi, i);
        accv = fmaf(wi, VP[(size_t)ii * E + h * HD + lane], accv);
      }
    } else {
      unsigned long long mask = __ballot(IN);
      while (mask) {
        const int b = __ffsll(mask) - 1; mask &= mask - 1;
        const float wi = __shfl(w, b);
        const int ii = __shfl(mi, b);
        accv = fmaf(wi, VP[(size_t)ii * E + h * HD + lane], accv);
      }
    }
    CTX[(size_t)row * E + h * HD + lane] = accv;
  }
}

extern "C" void kernel_launch(void* const* d_in, const int* in_sizes, int n_in,
                              void* d_out, int out_size, void* d_ws, size_t ws_size,
                              hipStream_t stream) {
  const float* query = (const float*)d_in[0];
  const float* key   = (const float*)d_in[1];
  const float* value = (const float*)d_in[2];
  const float* wq = (const float*)d_in[3];
  const float* bq = (const float*)d_in[4];
  const float* wk = (const float*)d_in[5];
  const float* bk = (const float*)d_in[6];
  const float* wv = (const float*)d_in[7];
  const float* bv = (const float*)d_in[8];
  const float* wo = (const float*)d_in[9];
  const float* bo = (const float*)d_in[10];

  float* out = (float*)d_out;                 // [S, E]
  float* am  = out + (size_t)S * E;           // [S, S]
  float* qp  = (float*)d_ws;                  // [S, E]
  float* kp  = qp + (size_t)S * E;
  float* vp  = kp + (size_t)S * E;
  float* ctx = vp + (size_t)S * E;

  hipMemsetAsync(am, 0, (size_t)S * S * sizeof(float), stream);

  const dim3 gg(S / 64, E / 64), bb(256);
  gemm_xwT<<<gg, bb, 0, stream>>>(query, wq, bq, qp, S, E, E);
  gemm_xwT<<<gg, bb, 0, stream>>>(key,   wk, bk, kp, S, E, E);
  gemm_xwT<<<gg, bb, 0, stream>>>(value, wv, bv, vp, S, E, E);

  attn_mfma<<<dim3(S / 16, NH), dim3(512), 0, stream>>>(qp, kp, vp, query, key,
                                                        wq, wk, ctx, am);

  gemm_xwT<<<gg, bb, 0, stream>>>(ctx, wo, bo, out, S, E, E);
}

// Round 11
// 635.019 us; speedup vs baseline: 1.0010x; 1.0010x over previous
//
#include <hip/hip_runtime.h>
#include <cstdint>

#define S 2048
#define E 1024
#define NH 16
#define HD 64
#define KTOP 32
#define BANDU 1e-3f       // unscaled-score ambiguity band
#define NPMAX 48

typedef __attribute__((ext_vector_type(8))) short short8v;   // bf16x8 frag
typedef __attribute__((ext_vector_type(4))) float f32x4;

// ---------------- fp32 GEMM: C[M,N] = X[M,K] @ W[N,K]^T + bias ----------------
__global__ __launch_bounds__(256)
void gemm_xwT(const float* __restrict__ X, const float* __restrict__ W,
              const float* __restrict__ bias, float* __restrict__ C,
              int M, int N, int K) {
  __shared__ float Xs[16][68];
  __shared__ float Ws[16][68];
  const int bm = blockIdx.x * 64;
  const int bn = blockIdx.y * 64;
  const int tid = threadIdx.x;
  const int tx = tid & 15, ty = tid >> 4;
  const int r = tid & 63, kk = (tid >> 6) * 4;
  float acc[4][4] = {};
  for (int k0 = 0; k0 < K; k0 += 16) {
    __syncthreads();
    {
      float4 xv = *(const float4*)(X + (size_t)(bm + r) * K + k0 + kk);
      Xs[kk + 0][r] = xv.x; Xs[kk + 1][r] = xv.y;
      Xs[kk + 2][r] = xv.z; Xs[kk + 3][r] = xv.w;
      float4 wv4 = *(const float4*)(W + (size_t)(bn + r) * K + k0 + kk);
      Ws[kk + 0][r] = wv4.x; Ws[kk + 1][r] = wv4.y;
      Ws[kk + 2][r] = wv4.z; Ws[kk + 3][r] = wv4.w;
    }
    __syncthreads();
#pragma unroll
    for (int k = 0; k < 16; ++k) {
      float4 a = *(const float4*)&Xs[k][tx * 4];
      float4 b = *(const float4*)&Ws[k][ty * 4];
      float av[4] = {a.x, a.y, a.z, a.w};
      float bv[4] = {b.x, b.y, b.z, b.w};
#pragma unroll
      for (int i = 0; i < 4; ++i)
#pragma unroll
        for (int j = 0; j < 4; ++j)
          acc[i][j] = fmaf(av[i], bv[j], acc[i][j]);
    }
  }
  const float4 bv4 = *(const float4*)(bias + bn + ty * 4);
  const float bb[4] = {bv4.x, bv4.y, bv4.z, bv4.w};
#pragma unroll
  for (int i = 0; i < 4; ++i) {
    float4 o;
    o.x = acc[i][0] + bb[0];
    o.y = acc[i][1] + bb[1];
    o.z = acc[i][2] + bb[2];
    o.w = acc[i][3] + bb[3];
    *(float4*)(C + (size_t)(bm + tx * 4 + i) * N + bn + ty * 4) = o;
  }
}

// ------------------------------ helpers --------------------------------------
__device__ __forceinline__ unsigned fordu(float x) {
  unsigned u = __float_as_uint(x);
  return (u & 0x80000000u) ? ~u : (u | 0x80000000u);
}
__device__ __forceinline__ float invfordu(unsigned f) {
  unsigned u = (f & 0x80000000u) ? (f ^ 0x80000000u) : ~f;
  return __uint_as_float(u);
}
__device__ __forceinline__ unsigned long long fordu64(double x) {
  unsigned long long u = (unsigned long long)__double_as_longlong(x);
  return (u >> 63) ? ~u : (u | 0x8000000000000000ULL);
}
__device__ __forceinline__ unsigned long long shflx64(unsigned long long v, int off) {
  int lo = __shfl_xor((int)(unsigned)(v & 0xFFFFFFFFULL), off);
  int hi = __shfl_xor((int)(unsigned)(v >> 32), off);
  return ((unsigned long long)(unsigned)hi << 32) | (unsigned)lo;
}
__device__ __forceinline__ double shflx_f64(double v, int off) {
  unsigned long long u = (unsigned long long)__double_as_longlong(v);
  return __longlong_as_double((long long)shflx64(u, off));
}
// round-to-nearest-even bf16 split: x ~= hi + lo (both bf16)
__device__ __forceinline__ void splitbf(float x, unsigned short& hs, unsigned short& ls) {
  unsigned u = __float_as_uint(x);
  unsigned r = (u + 0x7FFFu + ((u >> 16) & 1u)) & 0xFFFF0000u;
  hs = (unsigned short)(r >> 16);
  const float lo = x - __uint_as_float(r);
  unsigned ul = __float_as_uint(lo);
  ls = (unsigned short)((ul + 0x7FFFu + ((ul >> 16) & 1u)) >> 16);
}
// fp64 projection element: sum_e x[e]*w[e] (rare band path; biases are zero)
__device__ double proj64(const float* __restrict__ xrow, const float* __restrict__ wrow) {
  double a0 = 0.0, a1 = 0.0;
  for (int e = 0; e < E; e += 8) {
    const float4 x0 = *(const float4*)(xrow + e);
    const float4 w0 = *(const float4*)(wrow + e);
    const float4 x1 = *(const float4*)(xrow + e + 4);
    const float4 w1 = *(const float4*)(wrow + e + 4);
    a0 = fma((double)x0.x, (double)w0.x, a0);
    a0 = fma((double)x0.y, (double)w0.y, a0);
    a0 = fma((double)x0.z, (double)w0.z, a0);
    a0 = fma((double)x0.w, (double)w0.w, a0);
    a1 = fma((double)x1.x, (double)w1.x, a1);
    a1 = fma((double)x1.y, (double)w1.y, a1);
    a1 = fma((double)x1.z, (double)w1.z, a1);
    a1 = fma((double)x1.w, (double)w1.w, a1);
  }
  return a0 + a1;
}

// ==== fused: bf16-split MFMA scores + exact top-k + band fp64 + epilogue ======
// block = 512 thr (8 waves) x 16 q-rows x 1 head; wave owns 2 rows.
// per-lane score layout for row: idx(i,c): x=i*256+2l, y=+1, z=+128, w=+129
__global__ __launch_bounds__(512, 2)
void attn_mfma(const float* __restrict__ QP, const float* __restrict__ KP,
               const float* __restrict__ VP,
               const float* __restrict__ QRAW, const float* __restrict__ KRAW,
               const float* __restrict__ WQ, const float* __restrict__ WK,
               float* __restrict__ CTX, float* __restrict__ AM) {
  __shared__ short khi[128 * 64];          // 16KB, 16B-slot XOR swizzle by key&7
  __shared__ short klo[128 * 64];          // 16KB
  __shared__ short qhi[16 * 64];           // 2KB, swizzle by row&7
  __shared__ short qlo[16 * 64];           // 2KB
  __shared__ float sbuf[16][132];          // 8.4KB chunk scores [row][key]
  __shared__ unsigned long long cand[8][64];  // 4KB

  const int h = blockIdx.y;
  const int r0 = blockIdx.x * 16;
  const int tid = threadIdx.x;
  const int lane = tid & 63, wid = tid >> 6;
  const int wrow0 = wid * 2, wrow1 = wid * 2 + 1;

  // ---- stage Q (16x64), bf16 split ----
  if (tid < 256) {
    const int row = tid >> 4, d0 = (tid & 15) * 4;
    const float4 qv = *(const float4*)(QP + (size_t)(r0 + row) * E + h * HD + d0);
    unsigned short h0, h1, h2, h3, l0, l1, l2, l3;
    splitbf(qv.x, h0, l0); splitbf(qv.y, h1, l1);
    splitbf(qv.z, h2, l2); splitbf(qv.w, h3, l3);
    const int off = row * 64 + ((((d0 >> 3) ^ (row & 7)) << 3) + (d0 & 4));
    uint2 uh = {(unsigned)h0 | ((unsigned)h1 << 16), (unsigned)h2 | ((unsigned)h3 << 16)};
    uint2 ul = {(unsigned)l0 | ((unsigned)l1 << 16), (unsigned)l2 | ((unsigned)l3 << 16)};
    *(uint2*)&qhi[off] = uh;
    *(uint2*)&qlo[off] = ul;
  }
  __syncthreads();

  // ---- A-frags (all 16 rows), once ----
  const int arow = lane & 15, akg = lane >> 4, asw = arow & 7;
  const short8v ah0 = *(const short8v*)&qhi[arow * 64 + ((akg ^ asw) << 3)];
  const short8v ah1 = *(const short8v*)&qhi[arow * 64 + (((4 + akg) ^ asw) << 3)];
  const short8v al0 = *(const short8v*)&qlo[arow * 64 + ((akg ^ asw) << 3)];
  const short8v al1 = *(const short8v*)&qlo[arow * 64 + (((4 + akg) ^ asw) << 3)];

  f32x4 g[2][8];   // all indices literal (macro-expanded) -> registers

  auto stageK = [&](int c) {
    const int key = tid >> 2, dq = tid & 3;
    const float* src = KP + (size_t)(c * 128 + key) * E + h * HD;
    const int krow = key * 64, ksw = key & 7;
#pragma unroll
    for (int q2 = 0; q2 < 4; ++q2) {
      const int d0 = dq * 16 + q2 * 4;
      const float4 kv = *(const float4*)(src + d0);
      unsigned short h0, h1, h2, h3, l0, l1, l2, l3;
      splitbf(kv.x, h0, l0); splitbf(kv.y, h1, l1);
      splitbf(kv.z, h2, l2); splitbf(kv.w, h3, l3);
      const int off = krow + ((((d0 >> 3) ^ ksw) << 3) + (d0 & 4));
      uint2 uh = {(unsigned)h0 | ((unsigned)h1 << 16), (unsigned)h2 | ((unsigned)h3 << 16)};
      uint2 ul = {(unsigned)l0 | ((unsigned)l1 << 16), (unsigned)l2 | ((unsigned)l3 << 16)};
      *(uint2*)&khi[off] = uh;
      *(uint2*)&klo[off] = ul;
    }
  };

  auto mfmaPhase = [&]() {
    const int bcol = (wid << 4) + (lane & 15);
    const int bkg = lane >> 4, bsw = bcol & 7;
    const short8v bh0 = *(const short8v*)&khi[bcol * 64 + ((bkg ^ bsw) << 3)];
    const short8v bh1 = *(const short8v*)&khi[bcol * 64 + (((4 + bkg) ^ bsw) << 3)];
    const short8v bl0 = *(const short8v*)&klo[bcol * 64 + ((bkg ^ bsw) << 3)];
    const short8v bl1 = *(const short8v*)&klo[bcol * 64 + (((4 + bkg) ^ bsw) << 3)];
    f32x4 acc = {0.f, 0.f, 0.f, 0.f};
    acc = __builtin_amdgcn_mfma_f32_16x16x32_bf16(ah0, bh0, acc, 0, 0, 0);
    acc = __builtin_amdgcn_mfma_f32_16x16x32_bf16(ah1, bh1, acc, 0, 0, 0);
    acc = __builtin_amdgcn_mfma_f32_16x16x32_bf16(ah0, bl0, acc, 0, 0, 0);
    acc = __builtin_amdgcn_mfma_f32_16x16x32_bf16(ah1, bl1, acc, 0, 0, 0);
    acc = __builtin_amdgcn_mfma_f32_16x16x32_bf16(al0, bh0, acc, 0, 0, 0);
    acc = __builtin_amdgcn_mfma_f32_16x16x32_bf16(al1, bh1, acc, 0, 0, 0);
    const int dr0 = (lane >> 4) << 2;
    sbuf[dr0 + 0][bcol] = acc[0];
    sbuf[dr0 + 1][bcol] = acc[1];
    sbuf[dr0 + 2][bcol] = acc[2];
    sbuf[dr0 + 3][bcol] = acc[3];
  };

#define GREAD(cc) { \
    const float2 ta = *(const float2*)&sbuf[wrow0][lane * 2]; \
    const float2 tb = *(const float2*)&sbuf[wrow1][lane * 2]; \
    if ((cc) & 1) { g[0][(cc) >> 1].z = ta.x; g[0][(cc) >> 1].w = ta.y; \
                    g[1][(cc) >> 1].z = tb.x; g[1][(cc) >> 1].w = tb.y; } \
    else          { g[0][(cc) >> 1].x = ta.x; g[0][(cc) >> 1].y = ta.y; \
                    g[1][(cc) >> 1].x = tb.x; g[1][(cc) >> 1].y = tb.y; } }

  stageK(0); __syncthreads(); mfmaPhase(); __syncthreads();
#define STEP(c) stageK(c); GREAD((c) - 1); __syncthreads(); mfmaPhase(); __syncthreads();
  STEP(1) STEP(2) STEP(3) STEP(4) STEP(5) STEP(6) STEP(7) STEP(8)
  STEP(9) STEP(10) STEP(11) STEP(12) STEP(13) STEP(14) STEP(15)
  GREAD(15);
#undef STEP
#undef GREAD

  // -------- selection + epilogue per owned row (round-5 logic, new idx) -------
#pragma unroll
  for (int rr = 0; rr < 2; ++rr) {
    const int row = r0 + (wid << 1) + rr;
    float gm[8];
#pragma unroll
    for (int i = 0; i < 8; ++i)
      gm[i] = fmaxf(fmaxf(g[rr][i].x, g[rr][i].y), fmaxf(g[rr][i].z, g[rr][i].w));
    float lm = fmaxf(fmaxf(fmaxf(gm[0], gm[1]), fmaxf(gm[2], gm[3])),
                     fmaxf(fmaxf(gm[4], gm[5]), fmaxf(gm[6], gm[7])));

    // threshold T = 34th-largest lane-max (guarantees top-34 coverage)
    float sk = lm;
#pragma unroll
    for (int k = 2; k <= 64; k <<= 1)
#pragma unroll
      for (int j = k >> 1; j; j >>= 1) {
        const float o = __shfl_xor(sk, j);
        const float mx = fmaxf(sk, o), mn = fminf(sk, o);
        const bool up = ((lane & k) == 0);
        sk = (((lane & j) == 0) == up) ? mx : mn;
      }
    const float T = __shfl(sk, 33);

    int cnt = 0;
#pragma unroll
    for (int i = 0; i < 8; ++i)
      cnt += (g[rr][i].x >= T) + (g[rr][i].y >= T) + (g[rr][i].z >= T) + (g[rr][i].w >= T);
    int pre = cnt;
#pragma unroll
    for (int off = 1; off < 64; off <<= 1) {
      const int y = __shfl_up(pre, off);
      if (lane >= off) pre += y;
    }
    const int n = __shfl(pre, 63);

    float mv = -INFINITY; int mi = 0;
    if (n <= 64) {
      cand[wid][lane] = 0ULL;
      __threadfence_block();
      int pos = pre - cnt;
#pragma unroll
      for (int i = 0; i < 8; ++i) {
        const int bx = i * 256 + lane * 2;
        if (g[rr][i].x >= T) cand[wid][pos++] = (((unsigned long long)fordu(g[rr][i].x)) << 32) | (unsigned)(2047 - bx);
        if (g[rr][i].y >= T) cand[wid][pos++] = (((unsigned long long)fordu(g[rr][i].y)) << 32) | (unsigned)(2047 - (bx + 1));
        if (g[rr][i].z >= T) cand[wid][pos++] = (((unsigned long long)fordu(g[rr][i].z)) << 32) | (unsigned)(2047 - (bx + 128));
        if (g[rr][i].w >= T) cand[wid][pos++] = (((unsigned long long)fordu(g[rr][i].w)) << 32) | (unsigned)(2047 - (bx + 129));
      }
      __threadfence_block();
      unsigned long long key = cand[wid][lane];
#pragma unroll
      for (int k = 2; k <= 64; k <<= 1)
#pragma unroll
        for (int j = k >> 1; j; j >>= 1) {
          const unsigned long long o = shflx64(key, j);
          const unsigned long long mx = key > o ? key : o;
          const unsigned long long mn = key > o ? o : key;
          const bool up = ((lane & k) == 0);
          key = (((lane & j) == 0) == up) ? mx : mn;
        }
      if (lane < n) {
        mv = invfordu((unsigned)(key >> 32));
        mi = 2047 - (int)(key & 0xFFFFFFFFu);
      }
    } else {
      // rare fallback (massive ties): exact pop-max loop
      float v32f = -INFINITY, v33f = -INFINITY;
      bool stop = false;
#pragma unroll 1
      for (int p = 0; p < NPMAX && !stop; ++p) {
        float M = lm;
#pragma unroll
        for (int off = 32; off; off >>= 1) M = fmaxf(M, __shfl_xor(M, off));
        int fp = 0x7FFFFFFF;
#pragma unroll
        for (int i = 7; i >= 0; --i) {
          const int base = i * 256 + lane * 2;
          if (g[rr][i].w == M) fp = base + 129;
          if (g[rr][i].z == M) fp = base + 128;
          if (g[rr][i].y == M) fp = base + 1;
          if (g[rr][i].x == M) fp = base;
        }
        const unsigned long long bal = __ballot(lm == M);
        int widx;
        if (__popcll(bal) == 1) {
          widx = __shfl(fp, __ffsll(bal) - 1);
        } else {
          int c2m = (lm == M) ? fp : 0x7FFFFFFF;
#pragma unroll
          for (int off = 32; off; off >>= 1) c2m = min(c2m, __shfl_xor(c2m, off));
          widx = c2m;
        }
        const int og = widx >> 8, rem = widx & 255;
        const int ol = (rem >> 1) & 63;
        const int oc = ((rem >> 7) << 1) | (rem & 1);
        const bool own = (lane == ol);
#pragma unroll
        for (int i = 0; i < 8; ++i)
          if (og == i && own) {
            if (oc == 0) g[rr][i].x = -INFINITY;
            else if (oc == 1) g[rr][i].y = -INFINITY;
            else if (oc == 2) g[rr][i].z = -INFINITY;
            else g[rr][i].w = -INFINITY;
            gm[i] = fmaxf(fmaxf(g[rr][i].x, g[rr][i].y), fmaxf(g[rr][i].z, g[rr][i].w));
          }
        float m8 = fmaxf(fmaxf(fmaxf(gm[0], gm[1]), fmaxf(gm[2], gm[3])),
                         fmaxf(fmaxf(gm[4], gm[5]), fmaxf(gm[6], gm[7])));
        lm = own ? m8 : lm;
        if (lane == p) { mv = M; mi = widx; }
        if (p == 33) {
          v32f = __shfl(mv, 31); v33f = __shfl(mv, 32);
          stop = (v32f - v33f > BANDU);
        } else if (p > 33) {
          stop = (M < v32f - BANDU);
        }
      }
      // convert packed widx positions to real indices
      if (mv != -INFINITY) {
        const int og = mi >> 8, rem = mi & 255;
        mi = og * 256 + ((rem >> 7) << 7) + (((rem >> 1) & 63) * 2) + (rem & 1);
      }
    }

    const float v32 = __shfl(mv, 31), v33 = __shfl(mv, 32);
    const bool bandHit = (v32 - v33 <= BANDU);
    bool IN = (lane < KTOP);
    if (bandHit) {   // ambiguous cut (rare, wave-uniform)
      const bool flg = (mv >= v32 - BANDU) && (mv <= v33 + BANDU);
      const unsigned long long fmask = __ballot(flg);
      const int nAbove = __popcll(__ballot((lane < KTOP) && !flg));
      const int need = KTOP - nAbove;
      const double qd = proj64(QRAW + (size_t)row * E, WQ + (size_t)(h * HD + lane) * E);
      double s64 = -INFINITY;
      unsigned long long t = fmask;
      while (t) {
        const int f = __ffsll(t) - 1; t &= t - 1;
        const int ki = __shfl(mi, f);
        const double kd = proj64(KRAW + (size_t)ki * E, WK + (size_t)(h * HD + lane) * E);
        double sacc = qd * kd;
#pragma unroll
        for (int off = 32; off; off >>= 1) sacc += shflx_f64(sacc, off);
        if (lane == f) s64 = sacc;
      }
      bool in2 = false;
      for (int t2 = 0; t2 < need; ++t2) {
        const unsigned long long sk2 = (flg && !in2) ? fordu64(s64) : 0ULL;
        unsigned long long mx = sk2;
#pragma unroll
        for (int off = 32; off; off >>= 1) {
          const unsigned long long o = shflx64(mx, off);
          if (o > mx) mx = o;
        }
        const unsigned long long wb = __ballot(flg && !in2 && sk2 == mx);
        if (lane == __ffsll(wb) - 1) in2 = true;
      }
      IN = ((lane < KTOP) && !flg) || in2;
    }

    // softmax over IN (unscaled scores; scale 1/8 inside exp)
    float x = IN ? mv : -INFINITY, m = x;
#pragma unroll
    for (int off = 32; off; off >>= 1) m = fmaxf(m, __shfl_xor(m, off));
    const float ee = IN ? expf((mv - m) * 0.125f) : 0.f;
    float z = ee;
#pragma unroll
    for (int off = 32; off; off >>= 1) z += __shfl_xor(z, off);
    const float w = ee / z;
    if (IN) atomicAdd(AM + (size_t)row * S + mi, w * 0.0625f);

    float accv = 0.f;
    if (!bandHit) {
      // common path: IN == lanes 0..31 -> static, independent gathers
#pragma unroll
      for (int i = 0; i < KTOP; ++i) {
        const float wi = __shfl(w, i);
        const int ii = __shfl(mi, i);
        accv = fmaf(wi, VP[(size_t)ii * E + h * HD + lane], accv);
      }
    } else {
      unsigned long long mask = __ballot(IN);
      while (mask) {
        const int b = __ffsll(mask) - 1; mask &= mask - 1;
        const float wi = __shfl(w, b);
        const int ii = __shfl(mi, b);
        accv = fmaf(wi, VP[(size_t)ii * E + h * HD + lane], accv);
      }
    }
    CTX[(size_t)row * E + h * HD + lane] = accv;
  }
}

extern "C" void kernel_launch(void* const* d_in, const int* in_sizes, int n_in,
                              void* d_out, int out_size, void* d_ws, size_t ws_size,
                              hipStream_t stream) {
  const float* query = (const float*)d_in[0];
  const float* key   = (const float*)d_in[1];
  const float* value = (const float*)d_in[2];
  const float* wq = (const float*)d_in[3];
  const float* bq = (const float*)d_in[4];
  const float* wk = (const float*)d_in[5];
  const float* bk = (const float*)d_in[6];
  const float* wv = (const float*)d_in[7];
  const float* bv = (const float*)d_in[8];
  const float* wo = (const float*)d_in[9];
  const float* bo = (const float*)d_in[10];

  float* out = (float*)d_out;                 // [S, E]
  float* am  = out + (size_t)S * E;           // [S, S]
  float* qp  = (float*)d_ws;                  // [S, E]
  float* kp  = qp + (size_t)S * E;
  float* vp  = kp + (size_t)S * E;
  float* ctx = vp + (size_t)S * E;

  hipMemsetAsync(am, 0, (size_t)S * S * sizeof(float), stream);

  const dim3 gg(S / 64, E / 64), bb(256);
  gemm_xwT<<<gg, bb, 0, stream>>>(query, wq, bq, qp, S, E, E);
  gemm_xwT<<<gg, bb, 0, stream>>>(key,   wk, bk, kp, S, E, E);
  gemm_xwT<<<gg, bb, 0, stream>>>(value, wv, bv, vp, S, E, E);

  attn_mfma<<<dim3(S / 16, NH), dim3(512), 0, stream>>>(qp, kp, vp, query, key,
                                                        wq, wk, ctx, am);

  gemm_xwT<<<gg, bb, 0, stream>>>(ctx, wo, bo, out, S, E, E);
}

// Round 12
// 421.715 us; speedup vs baseline: 1.5074x; 1.5058x over previous
//
#include <hip/hip_runtime.h>
#include <cstdint>

#define S 2048
#define E 1024
#define NH 16
#define HD 64
#define KTOP 32
#define BANDU 1e-3f       // unscaled-score ambiguity band (score err ~5e-5 => 20 sigma)
#define NPMAX 48

typedef __attribute__((ext_vector_type(8))) short short8v;   // bf16x8 frag
typedef __attribute__((ext_vector_type(4))) float f32x4;

// ------------------------------ helpers --------------------------------------
__device__ __forceinline__ unsigned fordu(float x) {
  unsigned u = __float_as_uint(x);
  return (u & 0x80000000u) ? ~u : (u | 0x80000000u);
}
__device__ __forceinline__ float invfordu(unsigned f) {
  unsigned u = (f & 0x80000000u) ? (f ^ 0x80000000u) : ~f;
  return __uint_as_float(u);
}
__device__ __forceinline__ unsigned long long fordu64(double x) {
  unsigned long long u = (unsigned long long)__double_as_longlong(x);
  return (u >> 63) ? ~u : (u | 0x8000000000000000ULL);
}
__device__ __forceinline__ unsigned long long shflx64(unsigned long long v, int off) {
  int lo = __shfl_xor((int)(unsigned)(v & 0xFFFFFFFFULL), off);
  int hi = __shfl_xor((int)(unsigned)(v >> 32), off);
  return ((unsigned long long)(unsigned)hi << 32) | (unsigned)lo;
}
__device__ __forceinline__ double shflx_f64(double v, int off) {
  unsigned long long u = (unsigned long long)__double_as_longlong(v);
  return __longlong_as_double((long long)shflx64(u, off));
}
// round-to-nearest-even bf16 split: x ~= hi + lo (both bf16)
__device__ __forceinline__ void splitbf(float x, unsigned short& hs, unsigned short& ls) {
  unsigned u = __float_as_uint(x);
  unsigned r = (u + 0x7FFFu + ((u >> 16) & 1u)) & 0xFFFF0000u;
  hs = (unsigned short)(r >> 16);
  const float lo = x - __uint_as_float(r);
  unsigned ul = __float_as_uint(lo);
  ls = (unsigned short)((ul + 0x7FFFu + ((ul >> 16) & 1u)) >> 16);
}
// fp64 projection element: sum_e x[e]*w[e] (rare band path; exact vs reference)
__device__ double proj64(const float* __restrict__ xrow, const float* __restrict__ wrow) {
  double a0 = 0.0, a1 = 0.0;
  for (int e = 0; e < E; e += 8) {
    const float4 x0 = *(const float4*)(xrow + e);
    const float4 w0 = *(const float4*)(wrow + e);
    const float4 x1 = *(const float4*)(xrow + e + 4);
    const float4 w1 = *(const float4*)(wrow + e + 4);
    a0 = fma((double)x0.x, (double)w0.x, a0);
    a0 = fma((double)x0.y, (double)w0.y, a0);
    a0 = fma((double)x0.z, (double)w0.z, a0);
    a0 = fma((double)x0.w, (double)w0.w, a0);
    a1 = fma((double)x1.x, (double)w1.x, a1);
    a1 = fma((double)x1.y, (double)w1.y, a1);
    a1 = fma((double)x1.z, (double)w1.z, a1);
    a1 = fma((double)x1.w, (double)w1.w, a1);
  }
  return a0 + a1;
}

// ---------------- split fp32 array -> bf16 hi/lo arrays -----------------------
__global__ __launch_bounds__(256)
void split_bf(const float* __restrict__ X, unsigned short* __restrict__ XH,
              unsigned short* __restrict__ XL, int n4) {
  const int stride = gridDim.x * 256;
  for (int i = blockIdx.x * 256 + threadIdx.x; i < n4; i += stride) {
    const float4 v = ((const float4*)X)[i];
    ushort4 h4, l4;
    splitbf(v.x, h4.x, l4.x); splitbf(v.y, h4.y, l4.y);
    splitbf(v.z, h4.z, l4.z); splitbf(v.w, h4.w, l4.w);
    ((ushort4*)XH)[i] = h4;
    ((ushort4*)XL)[i] = l4;
  }
}

// ------- split-bf16 MFMA GEMM: C[M,N] = X[M,K] @ W[N,K]^T + bias --------------
// 3-pass (hh + hl + lh). block 256 (4 waves); tile 64x64; BK=32.
// mode 0: write fp32 C. mode 1: write split-bf16 CH/CL.
__global__ __launch_bounds__(256, 2)
void gemm_bsplit(const unsigned short* __restrict__ XH, const unsigned short* __restrict__ XL,
                 const unsigned short* __restrict__ WH, const unsigned short* __restrict__ WL,
                 const float* __restrict__ bias, float* __restrict__ C,
                 unsigned short* __restrict__ CH, unsigned short* __restrict__ CL,
                 int M, int N, int K, int mode) {
  __shared__ unsigned short Ah[64 * 32], Al[64 * 32];   // 4KB each
  __shared__ unsigned short Bh[64 * 32], Bl[64 * 32];
  const int bm = blockIdx.x * 64, bn = blockIdx.y * 64;
  const int tid = threadIdx.x, lane = tid & 63, wid = tid >> 6;
  const int qm = (wid >> 1) * 32, qn = (wid & 1) * 32;
  const int row = tid >> 2, slot = tid & 3;
  const size_t arow = (size_t)(bm + row) * K + slot * 8;
  const size_t brow = (size_t)(bn + row) * K + slot * 8;
  const int lds_off = row * 32 + slot * 8;

  f32x4 acc00 = {0,0,0,0}, acc01 = {0,0,0,0}, acc10 = {0,0,0,0}, acc11 = {0,0,0,0};

  // prologue stage k0=0
  *(uint4*)&Ah[lds_off] = *(const uint4*)&XH[arow];
  *(uint4*)&Al[lds_off] = *(const uint4*)&XL[arow];
  *(uint4*)&Bh[lds_off] = *(const uint4*)&WH[brow];
  *(uint4*)&Bl[lds_off] = *(const uint4*)&WL[brow];
  __syncthreads();

  const int fr = lane & 15, kg = lane >> 4;
  for (int k0 = 0; k0 < K; k0 += 32) {
    const bool more = (k0 + 32 < K);
    uint4 pah, pal, pbh, pbl;
    if (more) {                      // issue next-slab loads early (T14)
      pah = *(const uint4*)&XH[arow + k0 + 32];
      pal = *(const uint4*)&XL[arow + k0 + 32];
      pbh = *(const uint4*)&WH[brow + k0 + 32];
      pbl = *(const uint4*)&WL[brow + k0 + 32];
    }
    const short8v a0h = *(const short8v*)&Ah[(qm + fr) * 32 + kg * 8];
    const short8v a1h = *(const short8v*)&Ah[(qm + 16 + fr) * 32 + kg * 8];
    const short8v a0l = *(const short8v*)&Al[(qm + fr) * 32 + kg * 8];
    const short8v a1l = *(const short8v*)&Al[(qm + 16 + fr) * 32 + kg * 8];
    const short8v b0h = *(const short8v*)&Bh[(qn + fr) * 32 + kg * 8];
    const short8v b1h = *(const short8v*)&Bh[(qn + 16 + fr) * 32 + kg * 8];
    const short8v b0l = *(const short8v*)&Bl[(qn + fr) * 32 + kg * 8];
    const short8v b1l = *(const short8v*)&Bl[(qn + 16 + fr) * 32 + kg * 8];
    acc00 = __builtin_amdgcn_mfma_f32_16x16x32_bf16(a0h, b0h, acc00, 0, 0, 0);
    acc00 = __builtin_amdgcn_mfma_f32_16x16x32_bf16(a0h, b0l, acc00, 0, 0, 0);
    acc00 = __builtin_amdgcn_mfma_f32_16x16x32_bf16(a0l, b0h, acc00, 0, 0, 0);
    acc01 = __builtin_amdgcn_mfma_f32_16x16x32_bf16(a0h, b1h, acc01, 0, 0, 0);
    acc01 = __builtin_amdgcn_mfma_f32_16x16x32_bf16(a0h, b1l, acc01, 0, 0, 0);
    acc01 = __builtin_amdgcn_mfma_f32_16x16x32_bf16(a0l, b1h, acc01, 0, 0, 0);
    acc10 = __builtin_amdgcn_mfma_f32_16x16x32_bf16(a1h, b0h, acc10, 0, 0, 0);
    acc10 = __builtin_amdgcn_mfma_f32_16x16x32_bf16(a1h, b0l, acc10, 0, 0, 0);
    acc10 = __builtin_amdgcn_mfma_f32_16x16x32_bf16(a1l, b0h, acc10, 0, 0, 0);
    acc11 = __builtin_amdgcn_mfma_f32_16x16x32_bf16(a1h, b1h, acc11, 0, 0, 0);
    acc11 = __builtin_amdgcn_mfma_f32_16x16x32_bf16(a1h, b1l, acc11, 0, 0, 0);
    acc11 = __builtin_amdgcn_mfma_f32_16x16x32_bf16(a1l, b1h, acc11, 0, 0, 0);
    __syncthreads();
    if (more) {                      // commit prefetched slab
      *(uint4*)&Ah[lds_off] = pah;
      *(uint4*)&Al[lds_off] = pal;
      *(uint4*)&Bh[lds_off] = pbh;
      *(uint4*)&Bl[lds_off] = pbl;
    }
    __syncthreads();
  }

  // epilogue: D layout col=lane&15, row=(lane>>4)*4+reg  (validated mapping)
#pragma unroll
  for (int mt = 0; mt < 2; ++mt)
#pragma unroll
    for (int nt = 0; nt < 2; ++nt) {
      const f32x4 a = (mt == 0) ? (nt == 0 ? acc00 : acc01)
                                : (nt == 0 ? acc10 : acc11);
      const int n = bn + qn + nt * 16 + (lane & 15);
      const int m0 = bm + qm + mt * 16 + (lane >> 4) * 4;
      const float bv = bias[n];
#pragma unroll
      for (int r = 0; r < 4; ++r) {
        const float v = a[r] + bv;
        if (mode == 0) {
          C[(size_t)(m0 + r) * N + n] = v;
        } else {
          unsigned short hs, ls;
          splitbf(v, hs, ls);
          CH[(size_t)(m0 + r) * N + n] = hs;
          CL[(size_t)(m0 + r) * N + n] = ls;
        }
      }
    }
}

// ==== fused: bf16-split MFMA scores + exact top-k + band fp64 + epilogue ======
// block = 512 thr (8 waves) x 16 q-rows x 1 head; wave owns 2 rows.
// per-lane score layout for row: idx(i,c): x=i*256+2l, y=+1, z=+128, w=+129
__global__ __launch_bounds__(512, 2)
void attn_mfma(const unsigned short* __restrict__ QH, const unsigned short* __restrict__ QL,
               const unsigned short* __restrict__ KH, const unsigned short* __restrict__ KL,
               const float* __restrict__ VP,
               const float* __restrict__ QRAW, const float* __restrict__ KRAW,
               const float* __restrict__ WQ, const float* __restrict__ WK,
               float* __restrict__ CTX, float* __restrict__ AM) {
  __shared__ unsigned short khi[128 * 64];   // 16KB, 16B-slot XOR swizzle by key&7
  __shared__ unsigned short klo[128 * 64];   // 16KB
  __shared__ float sbuf[16][132];            // 8.25KB chunk scores [row][key]
  __shared__ unsigned long long cand[8][64]; // 4KB

  const int h = blockIdx.y;
  const int r0 = blockIdx.x * 16;
  const int tid = threadIdx.x;
  const int lane = tid & 63, wid = tid >> 6;
  const int wrow0 = wid * 2, wrow1 = wid * 2 + 1;

  // ---- A-frags direct from pre-split global Q ----
  const int arow = lane & 15, akg = lane >> 4;
  const unsigned short* qh = QH + (size_t)(r0 + arow) * E + h * HD;
  const unsigned short* ql = QL + (size_t)(r0 + arow) * E + h * HD;
  const short8v ah0 = *(const short8v*)(qh + akg * 8);
  const short8v ah1 = *(const short8v*)(qh + 32 + akg * 8);
  const short8v al0 = *(const short8v*)(ql + akg * 8);
  const short8v al1 = *(const short8v*)(ql + 32 + akg * 8);

  // ---- K staging: prefetch regs + commit (pre-split bf16) ----
  const int key = tid >> 2, dq = tid & 3;
  const int ksw = key & 7, krow = key * 64;
  uint4 ph0, ph1, pl0, pl1;
#define ISSUEK(c) { \
    const unsigned short* sh = KH + (size_t)((c) * 128 + key) * E + h * HD; \
    const unsigned short* sl = KL + (size_t)((c) * 128 + key) * E + h * HD; \
    ph0 = *(const uint4*)(sh + dq * 8); \
    ph1 = *(const uint4*)(sh + (4 + dq) * 8); \
    pl0 = *(const uint4*)(sl + dq * 8); \
    pl1 = *(const uint4*)(sl + (4 + dq) * 8); }
#define COMMITK() { \
    *(uint4*)&khi[krow + ((dq ^ ksw) << 3)] = ph0; \
    *(uint4*)&khi[krow + (((4 + dq) ^ ksw) << 3)] = ph1; \
    *(uint4*)&klo[krow + ((dq ^ ksw) << 3)] = pl0; \
    *(uint4*)&klo[krow + (((4 + dq) ^ ksw) << 3)] = pl1; }

  f32x4 g[2][8];   // scores, unscaled; all indices literal -> registers

  auto mfmaPhase = [&]() {
    const int bcol = (wid << 4) + (lane & 15);
    const int bkg = lane >> 4, bsw = bcol & 7;
    const short8v bh0 = *(const short8v*)&khi[bcol * 64 + ((bkg ^ bsw) << 3)];
    const short8v bh1 = *(const short8v*)&khi[bcol * 64 + (((4 + bkg) ^ bsw) << 3)];
    const short8v bl0 = *(const short8v*)&klo[bcol * 64 + ((bkg ^ bsw) << 3)];
    const short8v bl1 = *(const short8v*)&klo[bcol * 64 + (((4 + bkg) ^ bsw) << 3)];
    f32x4 acc = {0.f, 0.f, 0.f, 0.f};
    acc = __builtin_amdgcn_mfma_f32_16x16x32_bf16(ah0, bh0, acc, 0, 0, 0);
    acc = __builtin_amdgcn_mfma_f32_16x16x32_bf16(ah1, bh1, acc, 0, 0, 0);
    acc = __builtin_amdgcn_mfma_f32_16x16x32_bf16(ah0, bl0, acc, 0, 0, 0);
    acc = __builtin_amdgcn_mfma_f32_16x16x32_bf16(ah1, bl1, acc, 0, 0, 0);
    acc = __builtin_amdgcn_mfma_f32_16x16x32_bf16(al0, bh0, acc, 0, 0, 0);
    acc = __builtin_amdgcn_mfma_f32_16x16x32_bf16(al1, bh1, acc, 0, 0, 0);
    const int dr0 = (lane >> 4) << 2;
    sbuf[dr0 + 0][bcol] = acc[0];
    sbuf[dr0 + 1][bcol] = acc[1];
    sbuf[dr0 + 2][bcol] = acc[2];
    sbuf[dr0 + 3][bcol] = acc[3];
  };

#define GREAD(cc) { \
    const float2 ta = *(const float2*)&sbuf[wrow0][lane * 2]; \
    const float2 tb = *(const float2*)&sbuf[wrow1][lane * 2]; \
    if ((cc) & 1) { g[0][(cc) >> 1].z = ta.x; g[0][(cc) >> 1].w = ta.y; \
                    g[1][(cc) >> 1].z = tb.x; g[1][(cc) >> 1].w = tb.y; } \
    else          { g[0][(cc) >> 1].x = ta.x; g[0][(cc) >> 1].y = ta.y; \
                    g[1][(cc) >> 1].x = tb.x; g[1][(cc) >> 1].y = tb.y; } }

  ISSUEK(0); COMMITK();
  __syncthreads();
#define STEP(c) \
    if ((c) < 15) ISSUEK((c) + 1); \
    mfmaPhase(); \
    __syncthreads(); \
    GREAD(c); \
    if ((c) < 15) { COMMITK(); __syncthreads(); }
  STEP(0) STEP(1) STEP(2) STEP(3) STEP(4) STEP(5) STEP(6) STEP(7)
  STEP(8) STEP(9) STEP(10) STEP(11) STEP(12) STEP(13) STEP(14) STEP(15)
#undef STEP
#undef GREAD
#undef ISSUEK
#undef COMMITK

  // -------- selection + epilogue per owned row (validated round-5 logic) ------
#pragma unroll
  for (int rr = 0; rr < 2; ++rr) {
    const int row = r0 + (wid << 1) + rr;
    float gm[8];
#pragma unroll
    for (int i = 0; i < 8; ++i)
      gm[i] = fmaxf(fmaxf(g[rr][i].x, g[rr][i].y), fmaxf(g[rr][i].z, g[rr][i].w));
    float lm = fmaxf(fmaxf(fmaxf(gm[0], gm[1]), fmaxf(gm[2], gm[3])),
                     fmaxf(fmaxf(gm[4], gm[5]), fmaxf(gm[6], gm[7])));

    // threshold T = 34th-largest lane-max (guarantees top-34 coverage)
    float sk = lm;
#pragma unroll
    for (int k = 2; k <= 64; k <<= 1)
#pragma unroll
      for (int j = k >> 1; j; j >>= 1) {
        const float o = __shfl_xor(sk, j);
        const float mx = fmaxf(sk, o), mn = fminf(sk, o);
        const bool up = ((lane & k) == 0);
        sk = (((lane & j) == 0) == up) ? mx : mn;
      }
    const float T = __shfl(sk, 33);

    int cnt = 0;
#pragma unroll
    for (int i = 0; i < 8; ++i)
      cnt += (g[rr][i].x >= T) + (g[rr][i].y >= T) + (g[rr][i].z >= T) + (g[rr][i].w >= T);
    int pre = cnt;
#pragma unroll
    for (int off = 1; off < 64; off <<= 1) {
      const int y = __shfl_up(pre, off);
      if (lane >= off) pre += y;
    }
    const int n = __shfl(pre, 63);

    float mv = -INFINITY; int mi = 0;
    if (n <= 64) {
      cand[wid][lane] = 0ULL;
      __threadfence_block();
      int pos = pre - cnt;
#pragma unroll
      for (int i = 0; i < 8; ++i) {
        const int bx = i * 256 + lane * 2;
        if (g[rr][i].x >= T) cand[wid][pos++] = (((unsigned long long)fordu(g[rr][i].x)) << 32) | (unsigned)(2047 - bx);
        if (g[rr][i].y >= T) cand[wid][pos++] = (((unsigned long long)fordu(g[rr][i].y)) << 32) | (unsigned)(2047 - (bx + 1));
        if (g[rr][i].z >= T) cand[wid][pos++] = (((unsigned long long)fordu(g[rr][i].z)) << 32) | (unsigned)(2047 - (bx + 128));
        if (g[rr][i].w >= T) cand[wid][pos++] = (((unsigned long long)fordu(g[rr][i].w)) << 32) | (unsigned)(2047 - (bx + 129));
      }
      __threadfence_block();
      unsigned long long key2 = cand[wid][lane];
#pragma unroll
      for (int k = 2; k <= 64; k <<= 1)
#pragma unroll
        for (int j = k >> 1; j; j >>= 1) {
          const unsigned long long o = shflx64(key2, j);
          const unsigned long long mx = key2 > o ? key2 : o;
          const unsigned long long mn = key2 > o ? o : key2;
          const bool up = ((lane & k) == 0);
          key2 = (((lane & j) == 0) == up) ? mx : mn;
        }
      if (lane < n) {
        mv = invfordu((unsigned)(key2 >> 32));
        mi = 2047 - (int)(key2 & 0xFFFFFFFFu);
      }
    } else {
      // rare fallback (massive ties): exact pop-max loop
      float v32f = -INFINITY, v33f = -INFINITY;
      bool stop = false;
#pragma unroll 1
      for (int p = 0; p < NPMAX && !stop; ++p) {
        float M = lm;
#pragma unroll
        for (int off = 32; off; off >>= 1) M = fmaxf(M, __shfl_xor(M, off));
        int fp = 0x7FFFFFFF;
#pragma unroll
        for (int i = 7; i >= 0; --i) {
          const int base = i * 256 + lane * 2;
          if (g[rr][i].w == M) fp = base + 129;
          if (g[rr][i].z == M) fp = base + 128;
          if (g[rr][i].y == M) fp = base + 1;
          if (g[rr][i].x == M) fp = base;
        }
        const unsigned long long bal = __ballot(lm == M);
        int widx;
        if (__popcll(bal) == 1) {
          widx = __shfl(fp, __ffsll(bal) - 1);
        } else {
          int c2m = (lm == M) ? fp : 0x7FFFFFFF;
#pragma unroll
          for (int off = 32; off; off >>= 1) c2m = min(c2m, __shfl_xor(c2m, off));
          widx = c2m;
        }
        const int og = widx >> 8, rem = widx & 255;
        const int ol = (rem >> 1) & 63;
        const int oc = ((rem >> 7) << 1) | (rem & 1);
        const bool own = (lane == ol);
#pragma unroll
        for (int i = 0; i < 8; ++i)
          if (og == i && own) {
            if (oc == 0) g[rr][i].x = -INFINITY;
            else if (oc == 1) g[rr][i].y = -INFINITY;
            else if (oc == 2) g[rr][i].z = -INFINITY;
            else g[rr][i].w = -INFINITY;
            gm[i] = fmaxf(fmaxf(g[rr][i].x, g[rr][i].y), fmaxf(g[rr][i].z, g[rr][i].w));
          }
        float m8 = fmaxf(fmaxf(fmaxf(gm[0], gm[1]), fmaxf(gm[2], gm[3])),
                         fmaxf(fmaxf(gm[4], gm[5]), fmaxf(gm[6], gm[7])));
        lm = own ? m8 : lm;
        if (lane == p) { mv = M; mi = widx; }
        if (p == 33) {
          v32f = __shfl(mv, 31); v33f = __shfl(mv, 32);
          stop = (v32f - v33f > BANDU);
        } else if (p > 33) {
          stop = (M < v32f - BANDU);
        }
      }
      // convert packed widx positions to real indices
      if (mv != -INFINITY) {
        const int og = mi >> 8, rem = mi & 255;
        mi = og * 256 + ((rem >> 7) << 7) + (((rem >> 1) & 63) * 2) + (rem & 1);
      }
    }

    const float v32 = __shfl(mv, 31), v33 = __shfl(mv, 32);
    const bool bandHit = (v32 - v33 <= BANDU);
    bool IN = (lane < KTOP);
    if (bandHit) {   // ambiguous cut (rare, wave-uniform)
      const bool flg = (mv >= v32 - BANDU) && (mv <= v33 + BANDU);
      const unsigned long long fmask = __ballot(flg);
      const int nAbove = __popcll(__ballot((lane < KTOP) && !flg));
      const int need = KTOP - nAbove;
      const double qd = proj64(QRAW + (size_t)row * E, WQ + (size_t)(h * HD + lane) * E);
      double s64 = -INFINITY;
      unsigned long long t = fmask;
      while (t) {
        const int f = __ffsll(t) - 1; t &= t - 1;
        const int ki = __shfl(mi, f);
        const double kd = proj64(KRAW + (size_t)ki * E, WK + (size_t)(h * HD + lane) * E);
        double sacc = qd * kd;
#pragma unroll
        for (int off = 32; off; off >>= 1) sacc += shflx_f64(sacc, off);
        if (lane == f) s64 = sacc;
      }
      bool in2 = false;
      for (int t2 = 0; t2 < need; ++t2) {
        const unsigned long long sk2 = (flg && !in2) ? fordu64(s64) : 0ULL;
        unsigned long long mx = sk2;
#pragma unroll
        for (int off = 32; off; off >>= 1) {
          const unsigned long long o = shflx64(mx, off);
          if (o > mx) mx = o;
        }
        const unsigned long long wb = __ballot(flg && !in2 && sk2 == mx);
        if (lane == __ffsll(wb) - 1) in2 = true;
      }
      IN = ((lane < KTOP) && !flg) || in2;
    }

    // softmax over IN (unscaled scores; scale 1/8 inside exp)
    float x = IN ? mv : -INFINITY, m = x;
#pragma unroll
    for (int off = 32; off; off >>= 1) m = fmaxf(m, __shfl_xor(m, off));
    const float ee = IN ? expf((mv - m) * 0.125f) : 0.f;
    float z = ee;
#pragma unroll
    for (int off = 32; off; off >>= 1) z += __shfl_xor(z, off);
    const float w = ee / z;
    if (IN) atomicAdd(AM + (size_t)row * S + mi, w * 0.0625f);

    float accv = 0.f;
    if (!bandHit) {
      // common path: IN == lanes 0..31 -> static, independent gathers
#pragma unroll
      for (int i = 0; i < KTOP; ++i) {
        const float wi = __shfl(w, i);
        const int ii = __shfl(mi, i);
        accv = fmaf(wi, VP[(size_t)ii * E + h * HD + lane], accv);
      }
    } else {
      unsigned long long mask = __ballot(IN);
      while (mask) {
        const int b = __ffsll(mask) - 1; mask &= mask - 1;
        const float wi = __shfl(w, b);
        const int ii = __shfl(mi, b);
        accv = fmaf(wi, VP[(size_t)ii * E + h * HD + lane], accv);
      }
    }
    CTX[(size_t)row * E + h * HD + lane] = accv;
  }
}

extern "C" void kernel_launch(void* const* d_in, const int* in_sizes, int n_in,
                              void* d_out, int out_size, void* d_ws, size_t ws_size,
                              hipStream_t stream) {
  const float* query = (const float*)d_in[0];
  const float* key   = (const float*)d_in[1];
  const float* value = (const float*)d_in[2];
  const float* wq = (const float*)d_in[3];
  const float* bq = (const float*)d_in[4];
  const float* wk = (const float*)d_in[5];
  const float* bk = (const float*)d_in[6];
  const float* wv = (const float*)d_in[7];
  const float* bv = (const float*)d_in[8];
  const float* wo = (const float*)d_in[9];
  const float* bo = (const float*)d_in[10];

  float* out = (float*)d_out;                 // [S, E]
  float* am  = out + (size_t)S * E;           // [S, S]

  const size_t MB = 1ull << 20;
  char* w = (char*)d_ws;                              // 44 MB total (ws >= 48 MB)
  unsigned short* QHp = (unsigned short*)(w);         // 4 MB each
  unsigned short* QLp = (unsigned short*)(w + 4 * MB);
  unsigned short* KHp = (unsigned short*)(w + 8 * MB);
  unsigned short* KLp = (unsigned short*)(w + 12 * MB);
  float* vp  = (float*)(w + 16 * MB);                 // 8 MB
  float* ctx = (float*)(w + 24 * MB);                 // 8 MB
  unsigned short* XBH = (unsigned short*)(w + 32 * MB);  // 4 MB
  unsigned short* XBL = (unsigned short*)(w + 36 * MB);  // 4 MB
  unsigned short* WBH = (unsigned short*)(w + 40 * MB);  // 2 MB
  unsigned short* WBL = (unsigned short*)(w + 42 * MB);  // 2 MB

  hipMemsetAsync(am, 0, (size_t)S * S * sizeof(float), stream);

  const int nx4 = S * E / 4, nw4 = E * E / 4;
  const dim3 gg(S / 64, E / 64), bb(256);

  // Q projection -> split bf16
  split_bf<<<2048, bb, 0, stream>>>(query, XBH, XBL, nx4);
  split_bf<<<1024, bb, 0, stream>>>(wq, WBH, WBL, nw4);
  gemm_bsplit<<<gg, bb, 0, stream>>>(XBH, XBL, WBH, WBL, bq, nullptr, QHp, QLp,
                                     S, E, E, 1);
  // K projection -> split bf16
  split_bf<<<2048, bb, 0, stream>>>(key, XBH, XBL, nx4);
  split_bf<<<1024, bb, 0, stream>>>(wk, WBH, WBL, nw4);
  gemm_bsplit<<<gg, bb, 0, stream>>>(XBH, XBL, WBH, WBL, bk, nullptr, KHp, KLp,
                                     S, E, E, 1);
  // V projection -> fp32
  split_bf<<<2048, bb, 0, stream>>>(value, XBH, XBL, nx4);
  split_bf<<<1024, bb, 0, stream>>>(wv, WBH, WBL, nw4);
  gemm_bsplit<<<gg, bb, 0, stream>>>(XBH, XBL, WBH, WBL, bv, vp, nullptr, nullptr,
                                     S, E, E, 0);

  attn_mfma<<<dim3(S / 16, NH), dim3(512), 0, stream>>>(
      QHp, QLp, KHp, KLp, vp, query, key, wq, wk, ctx, am);

  // O projection -> fp32 out
  split_bf<<<2048, bb, 0, stream>>>(ctx, XBH, XBL, nx4);
  split_bf<<<1024, bb, 0, stream>>>(wo, WBH, WBL, nw4);
  gemm_bsplit<<<gg, bb, 0, stream>>>(XBH, XBL, WBH, WBL, bo, out, nullptr, nullptr,
                                     S, E, E, 0);
}